// Round 1
// baseline (113.523 us; speedup 1.0000x reference)
//
#include <hip/hip_runtime.h>

#define HW    36864
#define RST   136    // rel_s row stride (u16): 128 + 8 pad -> b128 reads 2-way only

typedef unsigned short u16;
typedef unsigned int   u32;
typedef __attribute__((ext_vector_type(8))) short bf16x8;
typedef __attribute__((ext_vector_type(4))) float f32x4;

__device__ __forceinline__ float bf2f(u32 u) {
    union { u32 i; float f; } c; c.i = u << 16; return c.f;
}
__device__ __forceinline__ u16 f2bf(float f) {
    union { float f; u32 i; } c; c.f = f;
    u32 r = (c.i + 0x7fffu + ((c.i >> 16) & 1u)) >> 16;  // RNE
    return (u16)r;
}
__device__ __forceinline__ u32 pack2(float a, float b) {
    return (u32)f2bf(a) | ((u32)f2bf(b) << 16);
}
__device__ __forceinline__ float sigf(float x) { return 1.0f / (1.0f + __expf(-x)); }

__device__ __forceinline__ void unpack8(uint4 v, float* o) {
    o[0] = bf2f(v.x & 0xffffu); o[1] = bf2f(v.x >> 16);
    o[2] = bf2f(v.y & 0xffffu); o[3] = bf2f(v.y >> 16);
    o[4] = bf2f(v.z & 0xffffu); o[5] = bf2f(v.z >> 16);
    o[6] = bf2f(v.w & 0xffffu); o[7] = bf2f(v.w >> 16);
}

// Block-wide dtype self-detect (same criterion that empirically selected the
// passing path in earlier rounds). Includes a barrier; call before any LDS
// use, all threads participating. Returns true if inputs are bf16.
__device__ __forceinline__ bool is_bf16_blk(const void* ml, int tid) {
    int pred = 0;
    if (tid < 128) {
        u16 v = ((const u16*)ml)[tid];
        u32 e = (v >> 7) & 0xffu;
        pred = ((v & 0x7fffu) == 0 || (e >= 90u && e <= 140u)) ? 1 : 0;
    }
    int cnt = __syncthreads_count(pred);
    return cnt >= 100;
}

// ---------------------------------------------------------------------------
// k_rel: relN[n][m] = relu(ov(n,m) - ov(m,n)) as bf16, row-major.
// grid 128 (n), block 256. Class term via cooperative per-class dot table:
//   d1[a] = sum_c u_s[c]*relu(WV[a,c]),  d2[a] = sum_c v_s[c]*relu(WU[a,c])
// computed with coalesced loads + shfl_xor reduction (replaces the old
// per-lane row-gather, ~64 cache lines per wave-load). Then per-m: table
// lookup + 64-wide pos loop. Runtime dtype branch (uniform).
// ---------------------------------------------------------------------------
__global__ __launch_bounds__(256) void k_rel(
    const void* __restrict__ ml,   const void* __restrict__ bbox,
    const void* __restrict__ WU,   const void* __restrict__ WV,
    const void* __restrict__ Wpos, const void* __restrict__ WP,
    const int* __restrict__ cls,   u16* __restrict__ relN)
{
    const int tid = threadIdx.x;
    const bool bf = is_bf16_blk(ml, tid);
    const int n = blockIdx.x;

    __shared__ float u_s[128], v_s[128], wpos_s[256], wpp_s[64], bbn_s[4];
    __shared__ float d1_s[80], d2_s[80];

    const int cn = cls[n] - 1;
    if (bf) {
        if (tid < 128) {
            float wp = bf2f(((const u16*)WP)[tid]);
            u_s[tid] = fmaxf(bf2f(((const u16*)WU)[cn * 128 + tid]), 0.f) * wp;
            v_s[tid] = fmaxf(bf2f(((const u16*)WV)[cn * 128 + tid]), 0.f) * wp;
        }
        wpos_s[tid] = bf2f(((const u16*)Wpos)[tid]);
        if (tid < 64) wpp_s[tid] = bf2f(((const u16*)WP)[128 + tid]);
        if (tid < 4)  bbn_s[tid] = bf2f(((const u16*)bbox)[n * 4 + tid]);
    } else {
        if (tid < 128) {
            float wp = ((const float*)WP)[tid];
            u_s[tid] = fmaxf(((const float*)WU)[cn * 128 + tid], 0.f) * wp;
            v_s[tid] = fmaxf(((const float*)WV)[cn * 128 + tid], 0.f) * wp;
        }
        wpos_s[tid] = ((const float*)Wpos)[tid];
        if (tid < 64) wpp_s[tid] = ((const float*)WP)[128 + tid];
        if (tid < 4)  bbn_s[tid] = ((const float*)bbox)[n * 4 + tid];
    }
    __syncthreads();

    // cooperative class-dot table: wave wv_ handles classes a = wv_, wv_+4, ...
    {
        const int wv_ = tid >> 6, lane = tid & 63;
        const float ua = u_s[lane], ub = u_s[64 + lane];
        const float va = v_s[lane], vb = v_s[64 + lane];
        for (int a = wv_; a < 80; a += 4) {
            float x0, x1, y0, y1;
            if (bf) {
                x0 = bf2f(((const u16*)WV)[a * 128 + lane]);
                x1 = bf2f(((const u16*)WV)[a * 128 + 64 + lane]);
                y0 = bf2f(((const u16*)WU)[a * 128 + lane]);
                y1 = bf2f(((const u16*)WU)[a * 128 + 64 + lane]);
            } else {
                x0 = ((const float*)WV)[a * 128 + lane];
                x1 = ((const float*)WV)[a * 128 + 64 + lane];
                y0 = ((const float*)WU)[a * 128 + lane];
                y1 = ((const float*)WU)[a * 128 + 64 + lane];
            }
            float p1 = ua * fmaxf(x0, 0.f) + ub * fmaxf(x1, 0.f);
            float p2 = va * fmaxf(y0, 0.f) + vb * fmaxf(y1, 0.f);
            #pragma unroll
            for (int o = 32; o; o >>= 1) {
                p1 += __shfl_xor(p1, o);
                p2 += __shfl_xor(p2, o);
            }
            if (lane == 0) { d1_s[a] = p1; d2_s[a] = p2; }
        }
    }
    __syncthreads();

    if (tid >= 128) return;
    const int m = tid;
    const int cm = cls[m] - 1;
    float s1 = d1_s[cm];
    float s2 = d2_s[cm];

    const float xmn = bbn_s[0], ymn = bbn_s[1], xMn = bbn_s[2], yMn = bbn_s[3];
    const float wn = xMn - xmn, hn = yMn - ymn;
    const float xcn = 0.5f * (xmn + xMn), ycn = 0.5f * (ymn + yMn);
    float xmm, ymm, xMm, yMm;
    if (bf) {
        xmm = bf2f(((const u16*)bbox)[m * 4 + 0]); ymm = bf2f(((const u16*)bbox)[m * 4 + 1]);
        xMm = bf2f(((const u16*)bbox)[m * 4 + 2]); yMm = bf2f(((const u16*)bbox)[m * 4 + 3]);
    } else {
        xmm = ((const float*)bbox)[m * 4 + 0]; ymm = ((const float*)bbox)[m * 4 + 1];
        xMm = ((const float*)bbox)[m * 4 + 2]; yMm = ((const float*)bbox)[m * 4 + 3];
    }
    const float wm = xMm - xmm, hm = yMm - ymm;
    const float xcm = 0.5f * (xmm + xMm), ycm = 0.5f * (ymm + yMm);

    const float p0 = -(xcn - xcm) / wn, p1 = -(ycn - ycm) / hn;
    const float p2 = __logf(wm / wn),   p3 = __logf(hm / hn);
    const float q0 = -(xcm - xcn) / wm, q1 = -(ycm - ycn) / hm;
    const float q2 = __logf(wn / wm),   q3 = __logf(hn / hm);

    #pragma unroll 8
    for (int d = 0; d < 64; ++d) {
        float w0 = wpos_s[d], w1 = wpos_s[64 + d], w2 = wpos_s[128 + d], w3 = wpos_s[192 + d];
        float wp = wpp_s[d];
        float t1 = p0 * w0 + p1 * w1 + p2 * w2 + p3 * w3;
        float t2 = q0 * w0 + q1 * w1 + q2 * w2 + q3 * w3;
        s1 += fmaxf(t1, 0.f) * wp;
        s2 += fmaxf(t2, 0.f) * wp;
    }

    float r = fmaxf(sigf(s1) - sigf(s2), 0.f);
    relN[n * 128 + m] = f2bf(r);
}

// ---------------------------------------------------------------------------
// k_main: out[n,px] = ml - ml*prob*(sum_m rel[n,m]*prob[m,px]) via MFMA.
// grid 576 x 256 threads (4 waves). Per block: n=128 full, px tile = 64
// (smaller tile -> 43 KB LDS -> 2-3 blocks/CU for latency hiding; per-block
// ml tile 32 KB stays L2-resident for the epilogue re-read).
// prob_s [64][64] u16 with 16B-chunk XOR swizzle: chunk_byte ^= quad(row)*32,
// quad(row) = (row&24)>>3 -> B-fragment ds_read_u16 are bank-conflict-free
// (was 4-way: all quads hit the same 8 banks with a 128B row stride).
// ---------------------------------------------------------------------------
__global__ __launch_bounds__(256, 2) void k_main(
    const void* __restrict__ mlv, const u16* __restrict__ relN,
    void* __restrict__ outv)
{
    const int tid = threadIdx.x;
    const bool bf = is_bf16_blk(mlv, tid);

    __shared__ u16 rel_s[128 * RST];   // 34816 B
    __shared__ u16 prob_s[64 * 64];    // 8192 B (swizzled)  total 43 KB

    const int px0  = blockIdx.x * 64;
    const int lane = tid & 63;
    const int col  = lane & 15;
    const int quad = lane >> 4;
    const int n0   = (tid >> 6) * 32;

    // stage rel: re-stride 128x128 -> 128xRST (coalesced b128 both sides)
    for (int idx = tid; idx < 2048; idx += 256) {
        int r = idx >> 4, c = idx & 15;
        uint4 v = ((const uint4*)relN)[idx];
        *(uint4*)(rel_s + r * RST + c * 8) = v;
    }

    f32x4 acc[2][4];
    #pragma unroll
    for (int i = 0; i < 2; ++i)
        #pragma unroll
        for (int t = 0; t < 4; ++t) acc[i][t] = (f32x4){0.f, 0.f, 0.f, 0.f};

    for (int h = 0; h < 2; ++h) {
        __syncthreads();   // rel copy done (h=0) / previous-half readers done (h=1)
        // stage prob_s = sigmoid(ml[h*64 .. h*64+63][px0 .. px0+63]) as bf16
        #pragma unroll
        for (int it = 0; it < 2; ++it) {
            int idx = tid + it * 256;          // < 512
            int r = idx >> 3, c8 = idx & 7;
            int qr = (r >> 3) & 3;
            size_t base = (size_t)(h * 64 + r) * HW + px0 + c8 * 8;
            float f[8];
            if (bf) {
                uint4 v = *(const uint4*)((const u16*)mlv + base);
                unpack8(v, f);
            } else {
                float4 v0 = *(const float4*)((const float*)mlv + base);
                float4 v1 = *(const float4*)((const float*)mlv + base + 4);
                f[0] = v0.x; f[1] = v0.y; f[2] = v0.z; f[3] = v0.w;
                f[4] = v1.x; f[5] = v1.y; f[6] = v1.z; f[7] = v1.w;
            }
            uint4 o;
            o.x = pack2(sigf(f[0]), sigf(f[1]));
            o.y = pack2(sigf(f[2]), sigf(f[3]));
            o.z = pack2(sigf(f[4]), sigf(f[5]));
            o.w = pack2(sigf(f[6]), sigf(f[7]));
            *(uint4*)((char*)prob_s + r * 128 + ((c8 * 16) ^ (qr * 32))) = o;
        }
        __syncthreads();

        #pragma unroll
        for (int ksl = 0; ksl < 2; ++ksl) {
            const int k0 = h * 64 + ksl * 32 + quad * 8;   // global k of this lane's 8
            bf16x8 a0 = *(const bf16x8*)(rel_s + (n0 + col) * RST + k0);
            bf16x8 a1 = *(const bf16x8*)(rel_s + (n0 + 16 + col) * RST + k0);
            const int rb = ksl * 32 + quad * 8;            // prob_s row base; quad(row)=quad
            #pragma unroll
            for (int t = 0; t < 4; ++t) {
                bf16x8 bfrag;
                #pragma unroll
                for (int j = 0; j < 8; ++j) {
                    bfrag[j] = (short)*(const u16*)((const char*)prob_s + (rb + j) * 128
                                                    + ((t * 32 + col * 2) ^ (quad * 32)));
                }
                acc[0][t] = __builtin_amdgcn_mfma_f32_16x16x32_bf16(a0, bfrag, acc[0][t], 0, 0, 0);
                acc[1][t] = __builtin_amdgcn_mfma_f32_16x16x32_bf16(a1, bfrag, acc[1][t], 0, 0, 0);
            }
        }
    }

    // epilogue: C/D layout col=lane&15, row=quad*4+reg; ml re-read is L2-hot
    #pragma unroll
    for (int i = 0; i < 2; ++i) {
        #pragma unroll
        for (int t = 0; t < 4; ++t) {
            const int nb = n0 + i * 16 + quad * 4;
            const int px = px0 + t * 16 + col;
            #pragma unroll
            for (int r = 0; r < 4; ++r) {
                size_t off = (size_t)(nb + r) * HW + px;
                if (bf) {
                    float mlvv = bf2f((u32)((const u16*)mlv)[off]);
                    float pr = sigf(mlvv);
                    ((u16*)outv)[off] = f2bf(mlvv - mlvv * pr * acc[i][t][r]);
                } else {
                    float mlvv = ((const float*)mlv)[off];
                    float pr = sigf(mlvv);
                    ((float*)outv)[off] = mlvv - mlvv * pr * acc[i][t][r];
                }
            }
        }
    }
}

extern "C" void kernel_launch(void* const* d_in, const int* in_sizes, int n_in,
                              void* d_out, int out_size, void* d_ws, size_t ws_size,
                              hipStream_t stream) {
    const void* ml   = d_in[0];
    const void* bbox = d_in[1];
    const void* WU   = d_in[2];
    const void* WV   = d_in[3];
    const void* Wpos = d_in[4];
    const void* WP   = d_in[5];
    const int*  cls  = (const int*)d_in[6];

    u16* relN = (u16*)d_ws;   // 32 KB, [n][m] row-major bf16

    k_rel<<<dim3(128), dim3(256), 0, stream>>>(ml, bbox, WU, WV, Wpos, WP, cls, relN);
    k_main<<<dim3(576), dim3(256), 0, stream>>>(ml, relN, d_out);
}

// Round 2
// 111.683 us; speedup vs baseline: 1.0165x; 1.0165x over previous
//
#include <hip/hip_runtime.h>

#define HW    36864
#define PXT   144    // px per block: 36864 / 256 blocks
#define RST   136    // rel_s row stride (u16): 128 + 8 pad -> b128 reads ~2-way (free)
#define PST   136    // prob_t px stride (u16): 272 B -> 4-bank rotation per px

typedef unsigned short u16;
typedef unsigned int   u32;
typedef __attribute__((ext_vector_type(8))) short bf16x8;
typedef __attribute__((ext_vector_type(4))) float f32x4;

__device__ __forceinline__ float bf2f(u32 u) {
    union { u32 i; float f; } c; c.i = u << 16; return c.f;
}
__device__ __forceinline__ u16 f2bf(float f) {
    union { float f; u32 i; } c; c.f = f;
    u32 r = (c.i + 0x7fffu + ((c.i >> 16) & 1u)) >> 16;  // RNE
    return (u16)r;
}
__device__ __forceinline__ u32 pack2(float a, float b) {
    return (u32)f2bf(a) | ((u32)f2bf(b) << 16);
}
__device__ __forceinline__ float sigf(float x) { return 1.0f / (1.0f + __expf(-x)); }

// Block-wide dtype self-detect (criterion empirically validated in earlier
// rounds). Includes a barrier; call before any LDS use, all threads.
__device__ __forceinline__ bool is_bf16_blk(const void* ml, int tid) {
    int pred = 0;
    if (tid < 128) {
        u16 v = ((const u16*)ml)[tid];
        u32 e = (v >> 7) & 0xffu;
        pred = ((v & 0x7fffu) == 0 || (e >= 90u && e <= 140u)) ? 1 : 0;
    }
    int cnt = __syncthreads_count(pred);
    return cnt >= 100;
}

// ---------------------------------------------------------------------------
// k_rel: relN[n][m] = relu(ov(n,m) - ov(m,n)) as bf16, row-major.
// grid 128 (n), block 256. Class term via cooperative per-class dot table
// (coalesced loads + shfl_xor reduce), then per-m lookup + 64-wide pos loop.
// ---------------------------------------------------------------------------
__global__ __launch_bounds__(256) void k_rel(
    const void* __restrict__ ml,   const void* __restrict__ bbox,
    const void* __restrict__ WU,   const void* __restrict__ WV,
    const void* __restrict__ Wpos, const void* __restrict__ WP,
    const int* __restrict__ cls,   u16* __restrict__ relN)
{
    const int tid = threadIdx.x;
    const bool bf = is_bf16_blk(ml, tid);
    const int n = blockIdx.x;

    __shared__ float u_s[128], v_s[128], wpos_s[256], wpp_s[64], bbn_s[4];
    __shared__ float d1_s[80], d2_s[80];

    const int cn = cls[n] - 1;
    if (bf) {
        if (tid < 128) {
            float wp = bf2f(((const u16*)WP)[tid]);
            u_s[tid] = fmaxf(bf2f(((const u16*)WU)[cn * 128 + tid]), 0.f) * wp;
            v_s[tid] = fmaxf(bf2f(((const u16*)WV)[cn * 128 + tid]), 0.f) * wp;
        }
        wpos_s[tid] = bf2f(((const u16*)Wpos)[tid]);
        if (tid < 64) wpp_s[tid] = bf2f(((const u16*)WP)[128 + tid]);
        if (tid < 4)  bbn_s[tid] = bf2f(((const u16*)bbox)[n * 4 + tid]);
    } else {
        if (tid < 128) {
            float wp = ((const float*)WP)[tid];
            u_s[tid] = fmaxf(((const float*)WU)[cn * 128 + tid], 0.f) * wp;
            v_s[tid] = fmaxf(((const float*)WV)[cn * 128 + tid], 0.f) * wp;
        }
        wpos_s[tid] = ((const float*)Wpos)[tid];
        if (tid < 64) wpp_s[tid] = ((const float*)WP)[128 + tid];
        if (tid < 4)  bbn_s[tid] = ((const float*)bbox)[n * 4 + tid];
    }
    __syncthreads();

    {
        const int wv_ = tid >> 6, lane = tid & 63;
        const float ua = u_s[lane], ub = u_s[64 + lane];
        const float va = v_s[lane], vb = v_s[64 + lane];
        for (int a = wv_; a < 80; a += 4) {
            float x0, x1, y0, y1;
            if (bf) {
                x0 = bf2f(((const u16*)WV)[a * 128 + lane]);
                x1 = bf2f(((const u16*)WV)[a * 128 + 64 + lane]);
                y0 = bf2f(((const u16*)WU)[a * 128 + lane]);
                y1 = bf2f(((const u16*)WU)[a * 128 + 64 + lane]);
            } else {
                x0 = ((const float*)WV)[a * 128 + lane];
                x1 = ((const float*)WV)[a * 128 + 64 + lane];
                y0 = ((const float*)WU)[a * 128 + lane];
                y1 = ((const float*)WU)[a * 128 + 64 + lane];
            }
            float p1 = ua * fmaxf(x0, 0.f) + ub * fmaxf(x1, 0.f);
            float p2 = va * fmaxf(y0, 0.f) + vb * fmaxf(y1, 0.f);
            #pragma unroll
            for (int o = 32; o; o >>= 1) {
                p1 += __shfl_xor(p1, o);
                p2 += __shfl_xor(p2, o);
            }
            if (lane == 0) { d1_s[a] = p1; d2_s[a] = p2; }
        }
    }
    __syncthreads();

    if (tid >= 128) return;
    const int m = tid;
    const int cm = cls[m] - 1;
    float s1 = d1_s[cm];
    float s2 = d2_s[cm];

    const float xmn = bbn_s[0], ymn = bbn_s[1], xMn = bbn_s[2], yMn = bbn_s[3];
    const float wn = xMn - xmn, hn = yMn - ymn;
    const float xcn = 0.5f * (xmn + xMn), ycn = 0.5f * (ymn + yMn);
    float xmm, ymm, xMm, yMm;
    if (bf) {
        xmm = bf2f(((const u16*)bbox)[m * 4 + 0]); ymm = bf2f(((const u16*)bbox)[m * 4 + 1]);
        xMm = bf2f(((const u16*)bbox)[m * 4 + 2]); yMm = bf2f(((const u16*)bbox)[m * 4 + 3]);
    } else {
        xmm = ((const float*)bbox)[m * 4 + 0]; ymm = ((const float*)bbox)[m * 4 + 1];
        xMm = ((const float*)bbox)[m * 4 + 2]; yMm = ((const float*)bbox)[m * 4 + 3];
    }
    const float wm = xMm - xmm, hm = yMm - ymm;
    const float xcm = 0.5f * (xmm + xMm), ycm = 0.5f * (ymm + yMm);

    const float p0 = -(xcn - xcm) / wn, p1 = -(ycn - ycm) / hn;
    const float p2 = __logf(wm / wn),   p3 = __logf(hm / hn);
    const float q0 = -(xcm - xcn) / wm, q1 = -(ycm - ycn) / hm;
    const float q2 = __logf(wn / wm),   q3 = __logf(hn / hm);

    #pragma unroll 8
    for (int d = 0; d < 64; ++d) {
        float w0 = wpos_s[d], w1 = wpos_s[64 + d], w2 = wpos_s[128 + d], w3 = wpos_s[192 + d];
        float wp = wpp_s[d];
        float t1 = p0 * w0 + p1 * w1 + p2 * w2 + p3 * w3;
        float t2 = q0 * w0 + q1 * w1 + q2 * w2 + q3 * w3;
        s1 += fmaxf(t1, 0.f) * wp;
        s2 += fmaxf(t2, 0.f) * wp;
    }

    float r = fmaxf(sigf(s1) - sigf(s2), 0.f);
    relN[n * 128 + m] = f2bf(r);
}

// ---------------------------------------------------------------------------
// k_main: out[n,px] = ml - ml*prob*(sum_m rel[n,m]*prob[m,px]) via MFMA.
// grid 256 x 512 threads (8 waves = 2 waves/SIMD; was 4 waves = 1/SIMD).
// Per block: n=128 full, px tile 144. Wave w owns n-tile [16w,16w+16), all
// 9 px-tiles. prob stored TRANSPOSED prob_t[px][k] (k contiguous) so the
// MFMA B-fragment is ONE ds_read_b128 instead of 8 ds_read_u16 (4x less LDS
// issue). PST=136 elems (272 B) rotates banks by 4 per px: staging b128
// writes conflict-free, frag reads ~2-way (free per m136). Single staging
// phase for all k=128 -> only 2 barriers in the kernel.
// ---------------------------------------------------------------------------
__global__ __launch_bounds__(512) void k_main(
    const void* __restrict__ mlv, const u16* __restrict__ relN,
    void* __restrict__ outv)
{
    const int tid = threadIdx.x;
    const bool bf = is_bf16_blk(mlv, tid);

    __shared__ u16 rel_s[128 * RST];    // 34816 B
    __shared__ u16 prob_t[PXT * PST];   // 39168 B  (total 74 KB)

    const int px0  = blockIdx.x * PXT;
    const int lane = tid & 63;
    const int col  = lane & 15;
    const int quad = lane >> 4;
    const int n0   = (tid >> 6) * 16;   // wave's n-tile base

    // stage rel: re-stride 128x128 -> 128xRST (coalesced b128 both sides)
    for (int idx = tid; idx < 2048; idx += 512) {
        int r = idx >> 4, c = idx & 15;
        uint4 v = ((const uint4*)relN)[idx];
        *(uint4*)(rel_s + r * RST + c * 8) = v;
    }

    // stage prob_t[px][k] = sigmoid(ml[k][px0+px]), k contiguous in groups of 8.
    // unit u -> (px = u % PXT, kg = u / PXT); consecutive lanes take
    // consecutive px at the same k -> coalesced global reads; b128 LDS write
    // per unit at stride 272 B -> conflict-free.
    for (int u = tid; u < PXT * 16; u += 512) {
        int px = u % PXT, kg = u / PXT;
        size_t gbase = (size_t)(kg * 8) * HW + px0 + px;
        float f[8];
        if (bf) {
            #pragma unroll
            for (int j = 0; j < 8; ++j)
                f[j] = bf2f((u32)((const u16*)mlv)[gbase + (size_t)j * HW]);
        } else {
            #pragma unroll
            for (int j = 0; j < 8; ++j)
                f[j] = ((const float*)mlv)[gbase + (size_t)j * HW];
        }
        uint4 o;
        o.x = pack2(sigf(f[0]), sigf(f[1]));
        o.y = pack2(sigf(f[2]), sigf(f[3]));
        o.z = pack2(sigf(f[4]), sigf(f[5]));
        o.w = pack2(sigf(f[6]), sigf(f[7]));
        *(uint4*)(prob_t + px * PST + kg * 8) = o;
    }
    __syncthreads();

    f32x4 acc[9];
    #pragma unroll
    for (int t = 0; t < 9; ++t) acc[t] = (f32x4){0.f, 0.f, 0.f, 0.f};

    #pragma unroll
    for (int ks = 0; ks < 4; ++ks) {
        const int k0 = ks * 32 + quad * 8;   // this lane's 8 k within the 32-slice
        bf16x8 a = *(const bf16x8*)(rel_s + (n0 + col) * RST + k0);
        #pragma unroll
        for (int t = 0; t < 9; ++t) {
            bf16x8 b = *(const bf16x8*)(prob_t + (t * 16 + col) * PST + k0);
            acc[t] = __builtin_amdgcn_mfma_f32_16x16x32_bf16(a, b, acc[t], 0, 0, 0);
        }
    }

    // epilogue: C/D layout col=lane&15, row=quad*4+reg; ml re-read is L2-hot
    #pragma unroll
    for (int t = 0; t < 9; ++t) {
        const int px = px0 + t * 16 + col;
        #pragma unroll
        for (int r = 0; r < 4; ++r) {
            size_t off = (size_t)(n0 + quad * 4 + r) * HW + px;
            if (bf) {
                float mlvv = bf2f((u32)((const u16*)mlv)[off]);
                float pr = sigf(mlvv);
                ((u16*)outv)[off] = f2bf(mlvv - mlvv * pr * acc[t][r]);
            } else {
                float mlvv = ((const float*)mlv)[off];
                float pr = sigf(mlvv);
                ((float*)outv)[off] = mlvv - mlvv * pr * acc[t][r];
            }
        }
    }
}

extern "C" void kernel_launch(void* const* d_in, const int* in_sizes, int n_in,
                              void* d_out, int out_size, void* d_ws, size_t ws_size,
                              hipStream_t stream) {
    const void* ml   = d_in[0];
    const void* bbox = d_in[1];
    const void* WU   = d_in[2];
    const void* WV   = d_in[3];
    const void* Wpos = d_in[4];
    const void* WP   = d_in[5];
    const int*  cls  = (const int*)d_in[6];

    u16* relN = (u16*)d_ws;   // 32 KB, [n][m] row-major bf16

    k_rel<<<dim3(128), dim3(256), 0, stream>>>(ml, bbox, WU, WV, Wpos, WP, cls, relN);
    k_main<<<dim3(256), dim3(512), 0, stream>>>(ml, relN, d_out);
}